// Round 5
// baseline (623.163 us; speedup 1.0000x reference)
//
#include <hip/hip_runtime.h>
#include <math.h>

#define HID 2048
#define ITR 1024
#define NEXP 8
#define TOPK 2
#define NTOK 2048
#define NSLOT (NTOK * TOPK)
#define MAXTT 40        // max 128-row tiles across experts (bound 4096/128+7=39)
#define SLOTS 80        // per-XCD slot count for block tables (bound 2*39=78)

typedef __attribute__((ext_vector_type(8))) short short8;
typedef __attribute__((ext_vector_type(4))) float f32x4;

__device__ __forceinline__ unsigned short f2bf(float f) {
    unsigned u = __float_as_uint(f);
    u += 0x7FFFu + ((u >> 16) & 1u);
    return (unsigned short)(u >> 16);
}

// ---------------- fused routing (single block) ----------------
__global__ void route_all_k(const int* __restrict__ idx,
                            const float* __restrict__ wts,
                            int* __restrict__ counts_g,
                            int* __restrict__ btok,
                            float* __restrict__ bw,
                            int* __restrict__ offs_g,
                            int* __restrict__ slotmap,
                            int* __restrict__ gu_tab,
                            int* __restrict__ dn_tab) {
    __shared__ int h[NEXP], nt[NEXP], pre[NEXP], base[NEXP], cur[NEXP];
    const int tid = threadIdx.x;
    if (tid < NEXP) { h[tid] = 0; cur[tid] = 0; }
    __syncthreads();
    for (int s = tid; s < NSLOT; s += 256) atomicAdd(&h[idx[s]], 1);
    __syncthreads();
    if (tid == 0) {
        int a = 0;
        for (int e = 0; e < NEXP; ++e) {
            base[e] = a; counts_g[e] = h[e]; offs_g[e] = a;
            int t = (h[e] + 127) >> 7; nt[e] = t; a += t << 7;
        }
        int p = 0;
        for (int e = 0; e < NEXP; ++e) { pre[e] = p; p += nt[e]; }
    }
    __syncthreads();
    for (int s = tid; s < NSLOT; s += 256) {
        int e = idx[s];
        int p = atomicAdd(&cur[e], 1);
        btok[e * NSLOT + p] = s >> 1;
        bw[e * NSLOT + p] = wts[s];
        slotmap[s] = base[e] + p;
    }
    for (int i = tid; i < 8 * SLOTS; i += 256) { gu_tab[i] = -1; dn_tab[i] = -1; }
    __syncthreads();
    // XCD-grouped tables: chunk c = e*16 + ib; xcd = ib&7, rank = ib>>3
    if (tid < 128) {
        int c = tid, e = c >> 4, ib = c & 15;
        int sb = 2 * pre[e] + (ib >> 3) * nt[e];
        for (int j = 0; j < nt[e]; ++j)
            gu_tab[(sb + j) * 8 + (ib & 7)] = (e << 16) | (ib << 8) | j;
    } else {
        int c = tid - 128, e = c >> 4, ib = c & 15;
        int sb = 2 * pre[e] + (ib >> 3) * nt[e];
        for (int j = 0; j < nt[e]; ++j)
            dn_tab[(sb + j) * 8 + (ib & 7)] = (e << 16) | (ib << 8) | j;
    }
}

// fp32 -> bf16, 8 elements/thread, one 16B store
__global__ void wconv8_k(const float* __restrict__ src, unsigned short* __restrict__ dst) {
    size_t i = ((size_t)blockIdx.x * 256 + threadIdx.x) * 8;
    float4 a = *(const float4*)(src + i);
    float4 b = *(const float4*)(src + i + 4);
    uint4 o;
    o.x = (unsigned)f2bf(a.x) | ((unsigned)f2bf(a.y) << 16);
    o.y = (unsigned)f2bf(a.z) | ((unsigned)f2bf(a.w) << 16);
    o.z = (unsigned)f2bf(b.x) | ((unsigned)f2bf(b.y) << 16);
    o.w = (unsigned)f2bf(b.z) | ((unsigned)f2bf(b.w) << 16);
    *(uint4*)(dst + i) = o;
}

// combine: out[t] = part[slot0[t]] + part[slot1[t]]
__global__ void combine_k(const float* __restrict__ part,
                          const int* __restrict__ slotmap,
                          float* __restrict__ out) {
    int gid = blockIdx.x * 256 + threadIdx.x;
    int t = gid >> 9;
    int c = gid & 511;
    int s0 = slotmap[t * 2], s1 = slotmap[t * 2 + 1];
    float4 a = ((const float4*)part)[(size_t)s0 * 512 + c];
    float4 b = ((const float4*)part)[(size_t)s1 * 512 + c];
    float4 r; r.x = a.x + b.x; r.y = a.y + b.y; r.z = a.z + b.z; r.w = a.w + b.w;
    ((float4*)out)[gid] = r;
}

// ================= MFMA path (bf16 weights) =================
#define BK 64
#define LDW 72

// Stage 1: M=128 x N=64 (x2 mats), K=2048
__launch_bounds__(256)
__global__ void moe_gu_k(const unsigned short* __restrict__ xb,
                         const unsigned short* __restrict__ gateb,
                         const unsigned short* __restrict__ upb,
                         const int* __restrict__ counts,
                         const int* __restrict__ btok,
                         const int* __restrict__ off,
                         const int* __restrict__ gu_tab,
                         unsigned short* __restrict__ interw) {
    const int v = gu_tab[blockIdx.x];
    if (v < 0) return;
    const int e    = v >> 16;
    const int iblk = (v >> 8) & 255;
    const int tile = v & 255;
    const int n = counts[e];

    __shared__ unsigned short s_a[128][LDW];
    __shared__ unsigned short s_bg[64][LDW];
    __shared__ unsigned short s_bu[64][LDW];
    __shared__ int s_tok[128];

    const int tid = threadIdx.x;
    if (tid < 128) {
        int tt = tile * 128 + tid;
        s_tok[tid] = btok[e * NSLOT + (tt < n ? tt : n - 1)];
    }
    __syncthreads();

    // A: 128x64 bf16 = 1024 16B chunks -> 4/thread
    const unsigned short* asrc[4];
    unsigned aoff[4];
    #pragma unroll
    for (int t = 0; t < 4; ++t) {
        int c = tid + t * 256;
        int r = c >> 3, col = (c & 7) * 8;
        asrc[t] = xb + (size_t)s_tok[r] * HID + col;
        aoff[t] = r * LDW + col;
    }
    // B: 64x64 bf16 per mat = 512 chunks -> 2/thread/mat
    const unsigned short* gbase = gateb + (size_t)e * ITR * HID + (size_t)iblk * 64 * HID;
    const unsigned short* ubase = upb   + (size_t)e * ITR * HID + (size_t)iblk * 64 * HID;
    unsigned boff[2], loff[2];
    #pragma unroll
    for (int t = 0; t < 2; ++t) {
        int c = tid + t * 256;
        int r = c >> 3, col = (c & 7) * 8;
        boff[t] = r * HID + col;
        loff[t] = r * LDW + col;
    }

    const int lane = tid & 63;
    const int w = tid >> 6;
    const int wm = (w & 1) * 64, wn = (w >> 1) * 32;
    const int l15 = lane & 15, quad = lane >> 4;

    f32x4 accg[4][2], accu[4][2];
    #pragma unroll
    for (int m = 0; m < 4; ++m)
        #pragma unroll
        for (int nn = 0; nn < 2; ++nn) {
            accg[m][nn] = (f32x4){0.f, 0.f, 0.f, 0.f};
            accu[m][nn] = (f32x4){0.f, 0.f, 0.f, 0.f};
        }

    unsigned short* s_flat_a = &s_a[0][0];
    unsigned short* s_flat_g = &s_bg[0][0];
    unsigned short* s_flat_u = &s_bu[0][0];

    uint4 pa[4], pg[2], pu[2];
    #pragma unroll
    for (int t = 0; t < 4; ++t) pa[t] = *(const uint4*)(asrc[t]);
    #pragma unroll
    for (int t = 0; t < 2; ++t) {
        pg[t] = *(const uint4*)(gbase + boff[t]);
        pu[t] = *(const uint4*)(ubase + boff[t]);
    }

    for (int k0 = 0; k0 < HID; k0 += BK) {
        #pragma unroll
        for (int t = 0; t < 4; ++t) *(uint4*)(s_flat_a + aoff[t]) = pa[t];
        #pragma unroll
        for (int t = 0; t < 2; ++t) {
            *(uint4*)(s_flat_g + loff[t]) = pg[t];
            *(uint4*)(s_flat_u + loff[t]) = pu[t];
        }
        __syncthreads();
        if (k0 + BK < HID) {
            #pragma unroll
            for (int t = 0; t < 4; ++t) pa[t] = *(const uint4*)(asrc[t] + k0 + BK);
            #pragma unroll
            for (int t = 0; t < 2; ++t) {
                pg[t] = *(const uint4*)(gbase + boff[t] + k0 + BK);
                pu[t] = *(const uint4*)(ubase + boff[t] + k0 + BK);
            }
        }
        #pragma unroll
        for (int kk = 0; kk < 2; ++kk) {
            const int kc = kk * 32 + quad * 8;
            short8 af[4], bg[2], bu[2];
            #pragma unroll
            for (int m = 0; m < 4; ++m)
                af[m] = *(const short8*)&s_a[wm + m * 16 + l15][kc];
            #pragma unroll
            for (int nn = 0; nn < 2; ++nn) {
                bg[nn] = *(const short8*)&s_bg[wn + nn * 16 + l15][kc];
                bu[nn] = *(const short8*)&s_bu[wn + nn * 16 + l15][kc];
            }
            #pragma unroll
            for (int m = 0; m < 4; ++m)
                #pragma unroll
                for (int nn = 0; nn < 2; ++nn) {
                    accg[m][nn] = __builtin_amdgcn_mfma_f32_16x16x32_bf16(af[m], bg[nn], accg[m][nn], 0, 0, 0);
                    accu[m][nn] = __builtin_amdgcn_mfma_f32_16x16x32_bf16(af[m], bu[nn], accu[m][nn], 0, 0, 0);
                }
        }
        __syncthreads();
    }

    const int pos0 = off[e] + tile * 128;
    #pragma unroll
    for (int m = 0; m < 4; ++m) {
        #pragma unroll
        for (int nn = 0; nn < 2; ++nn) {
            int col = iblk * 64 + wn + nn * 16 + l15;
            #pragma unroll
            for (int r = 0; r < 4; ++r) {
                int row = wm + m * 16 + quad * 4 + r;
                float g = accg[m][nn][r], u = accu[m][nn][r];
                float s = g / (1.0f + __expf(-g));
                interw[(size_t)(pos0 + row) * ITR + col] = f2bf(s * u);
            }
        }
    }
}

// Stage 2: M=128 x N=128, K=1024. mode 0: scaled partials; mode 1: atomicAdd
__launch_bounds__(256)
__global__ void moe_down_k(const unsigned short* __restrict__ interw,
                           const unsigned short* __restrict__ downb,
                           const int* __restrict__ counts,
                           const int* __restrict__ btok,
                           const float* __restrict__ bw,
                           const int* __restrict__ off,
                           const int* __restrict__ dn_tab,
                           float* __restrict__ dst,
                           int mode) {
    const int v = dn_tab[blockIdx.x];
    if (v < 0) return;
    const int e    = v >> 16;
    const int hblk = (v >> 8) & 255;
    const int tile = v & 255;
    const int n = counts[e];

    __shared__ unsigned short s_a[128][LDW];
    __shared__ unsigned short s_b[128][LDW];
    __shared__ int s_tok[128];
    __shared__ float s_w[128];

    const int tid = threadIdx.x;
    if (tid < 128) {
        int tt = tile * 128 + tid;
        bool vv = tt < n;
        s_tok[tid] = btok[e * NSLOT + (vv ? tt : n - 1)];
        s_w[tid] = vv ? bw[e * NSLOT + tt] : 0.0f;
    }
    __syncthreads();

    const int pos0 = off[e] + tile * 128;
    unsigned aoff[4], asrco[4];
    #pragma unroll
    for (int t = 0; t < 4; ++t) {
        int c = tid + t * 256;
        int r = c >> 3, col = (c & 7) * 8;
        asrco[t] = (unsigned)((pos0 + r) * ITR + col);
        aoff[t] = r * LDW + col;
    }
    // B: 128x64 bf16 = 1024 chunks -> 4/thread
    const unsigned short* dbase = downb + (size_t)e * HID * ITR + (size_t)hblk * 128 * ITR;
    unsigned boff[4], loff[4];
    #pragma unroll
    for (int t = 0; t < 4; ++t) {
        int c = tid + t * 256;
        int r = c >> 3, col = (c & 7) * 8;
        boff[t] = r * ITR + col;
        loff[t] = r * LDW + col;
    }

    const int lane = tid & 63;
    const int w = tid >> 6;
    const int wm = (w & 1) * 64, wn = (w >> 1) * 64;
    const int l15 = lane & 15, quad = lane >> 4;

    f32x4 acc[4][4];
    #pragma unroll
    for (int m = 0; m < 4; ++m)
        #pragma unroll
        for (int nn = 0; nn < 4; ++nn) acc[m][nn] = (f32x4){0.f, 0.f, 0.f, 0.f};

    unsigned short* s_flat_a = &s_a[0][0];
    unsigned short* s_flat_b = &s_b[0][0];

    uint4 pa[4], pb[4];
    #pragma unroll
    for (int t = 0; t < 4; ++t) {
        pa[t] = *(const uint4*)(interw + asrco[t]);
        pb[t] = *(const uint4*)(dbase + boff[t]);
    }

    for (int k0 = 0; k0 < ITR; k0 += BK) {
        #pragma unroll
        for (int t = 0; t < 4; ++t) {
            *(uint4*)(s_flat_a + aoff[t]) = pa[t];
            *(uint4*)(s_flat_b + loff[t]) = pb[t];
        }
        __syncthreads();
        if (k0 + BK < ITR) {
            #pragma unroll
            for (int t = 0; t < 4; ++t) {
                pa[t] = *(const uint4*)(interw + asrco[t] + k0 + BK);
                pb[t] = *(const uint4*)(dbase + boff[t] + k0 + BK);
            }
        }
        #pragma unroll
        for (int kk = 0; kk < 2; ++kk) {
            const int kc = kk * 32 + quad * 8;
            short8 af[4], bf[4];
            #pragma unroll
            for (int m = 0; m < 4; ++m)
                af[m] = *(const short8*)&s_a[wm + m * 16 + l15][kc];
            #pragma unroll
            for (int nn = 0; nn < 4; ++nn)
                bf[nn] = *(const short8*)&s_b[wn + nn * 16 + l15][kc];
            #pragma unroll
            for (int m = 0; m < 4; ++m)
                #pragma unroll
                for (int nn = 0; nn < 4; ++nn)
                    acc[m][nn] = __builtin_amdgcn_mfma_f32_16x16x32_bf16(af[m], bf[nn], acc[m][nn], 0, 0, 0);
        }
        __syncthreads();
    }

    if (mode == 0) {
        #pragma unroll
        for (int m = 0; m < 4; ++m) {
            #pragma unroll
            for (int nn = 0; nn < 4; ++nn) {
                int col = hblk * 128 + wn + nn * 16 + l15;
                #pragma unroll
                for (int r = 0; r < 4; ++r) {
                    int row = wm + m * 16 + quad * 4 + r;
                    dst[(size_t)(pos0 + row) * HID + col] = s_w[row] * acc[m][nn][r];
                }
            }
        }
    } else {
        #pragma unroll
        for (int m = 0; m < 4; ++m) {
            #pragma unroll
            for (int nn = 0; nn < 4; ++nn) {
                int col = hblk * 128 + wn + nn * 16 + l15;
                #pragma unroll
                for (int r = 0; r < 4; ++r) {
                    int row = wm + m * 16 + quad * 4 + r;
                    atomicAdd(&dst[(size_t)s_tok[row] * HID + col], s_w[row] * acc[m][nn][r]);
                }
            }
        }
    }
}

// ================= fp32-weight fallback GEMMs (R4 path, used if ws too small) =================
__launch_bounds__(256)
__global__ void moe_gu_f32_k(const unsigned short* __restrict__ xb,
                             const float* __restrict__ gate,
                             const float* __restrict__ up,
                             const int* __restrict__ counts,
                             const int* __restrict__ btok,
                             const int* __restrict__ off,
                             const int* __restrict__ gu_tab,
                             unsigned short* __restrict__ interw) {
    const int v = gu_tab[blockIdx.x];
    if (v < 0) return;
    const int e    = v >> 16;
    const int iblk = (v >> 8) & 255;
    const int tile = v & 255;
    const int n = counts[e];

    __shared__ unsigned short s_a[128][LDW];
    __shared__ unsigned short s_bg[64][LDW];
    __shared__ unsigned short s_bu[64][LDW];
    __shared__ int s_tok[128];

    const int tid = threadIdx.x;
    if (tid < 128) {
        int tt = tile * 128 + tid;
        s_tok[tid] = btok[e * NSLOT + (tt < n ? tt : n - 1)];
    }
    __syncthreads();

    const unsigned short* asrc[4];
    unsigned aoff[4];
    #pragma unroll
    for (int t = 0; t < 4; ++t) {
        int c = tid + t * 256;
        int r = c >> 3, col = (c & 7) * 8;
        asrc[t] = xb + (size_t)s_tok[r] * HID + col;
        aoff[t] = r * LDW + col;
    }
    const float* gbase = gate + (size_t)e * ITR * HID + (size_t)iblk * 64 * HID;
    const float* ubase = up   + (size_t)e * ITR * HID + (size_t)iblk * 64 * HID;
    unsigned boff[4], loff[4];
    #pragma unroll
    for (int t = 0; t < 4; ++t) {
        int f = tid + t * 256;
        int r = f >> 4, col = (f & 15) * 4;
        boff[t] = r * HID + col;
        loff[t] = r * LDW + col;
    }

    const int lane = tid & 63;
    const int w = tid >> 6;
    const int wm = (w & 1) * 64, wn = (w >> 1) * 32;
    const int l15 = lane & 15, quad = lane >> 4;

    f32x4 accg[4][2], accu[4][2];
    #pragma unroll
    for (int m = 0; m < 4; ++m)
        #pragma unroll
        for (int nn = 0; nn < 2; ++nn) {
            accg[m][nn] = (f32x4){0.f, 0.f, 0.f, 0.f};
            accu[m][nn] = (f32x4){0.f, 0.f, 0.f, 0.f};
        }

    unsigned short* s_flat_a = &s_a[0][0];
    unsigned short* s_flat_g = &s_bg[0][0];
    unsigned short* s_flat_u = &s_bu[0][0];

    uint4 pa[4];
    float4 pg[4], pu[4];
    #pragma unroll
    for (int t = 0; t < 4; ++t) {
        pa[t] = *(const uint4*)(asrc[t]);
        pg[t] = *(const float4*)(gbase + boff[t]);
        pu[t] = *(const float4*)(ubase + boff[t]);
    }

    for (int k0 = 0; k0 < HID; k0 += BK) {
        #pragma unroll
        for (int t = 0; t < 4; ++t) {
            *(uint4*)(s_flat_a + aoff[t]) = pa[t];
            ushort4 gb, ub;
            gb.x = f2bf(pg[t].x); gb.y = f2bf(pg[t].y); gb.z = f2bf(pg[t].z); gb.w = f2bf(pg[t].w);
            ub.x = f2bf(pu[t].x); ub.y = f2bf(pu[t].y); ub.z = f2bf(pu[t].z); ub.w = f2bf(pu[t].w);
            *(ushort4*)(s_flat_g + loff[t]) = gb;
            *(ushort4*)(s_flat_u + loff[t]) = ub;
        }
        __syncthreads();
        if (k0 + BK < HID) {
            #pragma unroll
            for (int t = 0; t < 4; ++t) {
                pa[t] = *(const uint4*)(asrc[t] + k0 + BK);
                pg[t] = *(const float4*)(gbase + boff[t] + k0 + BK);
                pu[t] = *(const float4*)(ubase + boff[t] + k0 + BK);
            }
        }
        #pragma unroll
        for (int kk = 0; kk < 2; ++kk) {
            const int kc = kk * 32 + quad * 8;
            short8 af[4], bg[2], bu[2];
            #pragma unroll
            for (int m = 0; m < 4; ++m)
                af[m] = *(const short8*)&s_a[wm + m * 16 + l15][kc];
            #pragma unroll
            for (int nn = 0; nn < 2; ++nn) {
                bg[nn] = *(const short8*)&s_bg[wn + nn * 16 + l15][kc];
                bu[nn] = *(const short8*)&s_bu[wn + nn * 16 + l15][kc];
            }
            #pragma unroll
            for (int m = 0; m < 4; ++m)
                #pragma unroll
                for (int nn = 0; nn < 2; ++nn) {
                    accg[m][nn] = __builtin_amdgcn_mfma_f32_16x16x32_bf16(af[m], bg[nn], accg[m][nn], 0, 0, 0);
                    accu[m][nn] = __builtin_amdgcn_mfma_f32_16x16x32_bf16(af[m], bu[nn], accu[m][nn], 0, 0, 0);
                }
        }
        __syncthreads();
    }

    const int pos0 = off[e] + tile * 128;
    #pragma unroll
    for (int m = 0; m < 4; ++m) {
        #pragma unroll
        for (int nn = 0; nn < 2; ++nn) {
            int col = iblk * 64 + wn + nn * 16 + l15;
            #pragma unroll
            for (int r = 0; r < 4; ++r) {
                int row = wm + m * 16 + quad * 4 + r;
                float g = accg[m][nn][r], u = accu[m][nn][r];
                float s = g / (1.0f + __expf(-g));
                interw[(size_t)(pos0 + row) * ITR + col] = f2bf(s * u);
            }
        }
    }
}

__launch_bounds__(256)
__global__ void moe_down_f32_k(const unsigned short* __restrict__ interw,
                               const float* __restrict__ down,
                               const int* __restrict__ counts,
                               const int* __restrict__ btok,
                               const float* __restrict__ bw,
                               const int* __restrict__ off,
                               const int* __restrict__ dn_tab,
                               float* __restrict__ dst) {
    const int v = dn_tab[blockIdx.x];
    if (v < 0) return;
    const int e    = v >> 16;
    const int hblk = (v >> 8) & 255;
    const int tile = v & 255;
    const int n = counts[e];

    __shared__ unsigned short s_a[128][LDW];
    __shared__ unsigned short s_b[128][LDW];
    __shared__ int s_tok[128];
    __shared__ float s_w[128];

    const int tid = threadIdx.x;
    if (tid < 128) {
        int tt = tile * 128 + tid;
        bool vv = tt < n;
        s_tok[tid] = btok[e * NSLOT + (vv ? tt : n - 1)];
        s_w[tid] = vv ? bw[e * NSLOT + tt] : 0.0f;
    }
    __syncthreads();

    const int pos0 = off[e] + tile * 128;
    unsigned aoff[4], asrco[4];
    #pragma unroll
    for (int t = 0; t < 4; ++t) {
        int c = tid + t * 256;
        int r = c >> 3, col = (c & 7) * 8;
        asrco[t] = (unsigned)((pos0 + r) * ITR + col);
        aoff[t] = r * LDW + col;
    }
    const float* dbase = down + (size_t)e * HID * ITR + (size_t)hblk * 128 * ITR;
    unsigned boff[8], loff[8];
    #pragma unroll
    for (int t = 0; t < 8; ++t) {
        int f = tid + t * 256;
        int r = f >> 4, col = (f & 15) * 4;
        boff[t] = r * ITR + col;
        loff[t] = r * LDW + col;
    }

    const int lane = tid & 63;
    const int w = tid >> 6;
    const int wm = (w & 1) * 64, wn = (w >> 1) * 64;
    const int l15 = lane & 15, quad = lane >> 4;

    f32x4 acc[4][4];
    #pragma unroll
    for (int m = 0; m < 4; ++m)
        #pragma unroll
        for (int nn = 0; nn < 4; ++nn) acc[m][nn] = (f32x4){0.f, 0.f, 0.f, 0.f};

    unsigned short* s_flat_a = &s_a[0][0];
    unsigned short* s_flat_b = &s_b[0][0];

    uint4 pa[4];
    float4 pb[8];
    #pragma unroll
    for (int t = 0; t < 4; ++t) pa[t] = *(const uint4*)(interw + asrco[t]);
    #pragma unroll
    for (int t = 0; t < 8; ++t) pb[t] = *(const float4*)(dbase + boff[t]);

    for (int k0 = 0; k0 < ITR; k0 += BK) {
        #pragma unroll
        for (int t = 0; t < 4; ++t)
            *(uint4*)(s_flat_a + aoff[t]) = pa[t];
        #pragma unroll
        for (int t = 0; t < 8; ++t) {
            ushort4 b;
            b.x = f2bf(pb[t].x); b.y = f2bf(pb[t].y); b.z = f2bf(pb[t].z); b.w = f2bf(pb[t].w);
            *(ushort4*)(s_flat_b + loff[t]) = b;
        }
        __syncthreads();
        if (k0 + BK < ITR) {
            #pragma unroll
            for (int t = 0; t < 4; ++t) pa[t] = *(const uint4*)(interw + asrco[t] + k0 + BK);
            #pragma unroll
            for (int t = 0; t < 8; ++t) pb[t] = *(const float4*)(dbase + boff[t] + k0 + BK);
        }
        #pragma unroll
        for (int kk = 0; kk < 2; ++kk) {
            const int kc = kk * 32 + quad * 8;
            short8 af[4], bf[4];
            #pragma unroll
            for (int m = 0; m < 4; ++m)
                af[m] = *(const short8*)&s_a[wm + m * 16 + l15][kc];
            #pragma unroll
            for (int nn = 0; nn < 4; ++nn)
                bf[nn] = *(const short8*)&s_b[wn + nn * 16 + l15][kc];
            #pragma unroll
            for (int m = 0; m < 4; ++m)
                #pragma unroll
                for (int nn = 0; nn < 4; ++nn)
                    acc[m][nn] = __builtin_amdgcn_mfma_f32_16x16x32_bf16(af[m], bf[nn], acc[m][nn], 0, 0, 0);
        }
        __syncthreads();
    }

    #pragma unroll
    for (int m = 0; m < 4; ++m) {
        #pragma unroll
        for (int nn = 0; nn < 4; ++nn) {
            int col = hblk * 128 + wn + nn * 16 + l15;
            #pragma unroll
            for (int r = 0; r < 4; ++r) {
                int row = wm + m * 16 + quad * 4 + r;
                atomicAdd(&dst[(size_t)s_tok[row] * HID + col], s_w[row] * acc[m][nn][r]);
            }
        }
    }
}

extern "C" void kernel_launch(void* const* d_in, const int* in_sizes, int n_in,
                              void* d_out, int out_size, void* d_ws, size_t ws_size,
                              hipStream_t stream) {
    const float* x    = (const float*)d_in[0];
    const int*   idx  = (const int*)d_in[1];
    const float* wts  = (const float*)d_in[2];
    const float* gate = (const float*)d_in[3];
    const float* up   = (const float*)d_in[4];
    const float* down = (const float*)d_in[5];
    float* out = (float*)d_out;

    // ws layout
    const size_t off_btok  = 256;
    const size_t off_bw    = off_btok + (size_t)NEXP * NSLOT * 4;
    const size_t off_offs  = off_bw + (size_t)NEXP * NSLOT * 4;
    const size_t off_smap  = off_offs + 256;
    const size_t off_tabs  = off_smap + (size_t)NSLOT * 4;
    const size_t off_xb    = off_tabs + 2 * 8 * SLOTS * 4;
    const size_t off_inter = off_xb + (size_t)NTOK * HID * 2;
    const size_t off_wb    = off_inter + (size_t)(MAXTT * 128) * ITR * 2;
    const size_t WSZ       = (size_t)NEXP * ITR * HID * 2;               // 32 MB per weight tensor (bf16)
    const size_t off_part  = off_wb + 3 * WSZ;
    const size_t need_old  = off_wb;                                     // ~19 MB: fp32-weight path
    const size_t need_mid  = off_part;                                   // ~115 MB: bf16 weights, atomic down
    const size_t need_full = off_part + (size_t)(MAXTT * 128) * HID * 4; // ~155 MB: + partials

    int*   counts = (int*)d_ws;
    int*   btok   = (int*)((char*)d_ws + off_btok);
    float* bw     = (float*)((char*)d_ws + off_bw);
    int*   offs   = (int*)((char*)d_ws + off_offs);
    int*   smap   = (int*)((char*)d_ws + off_smap);
    int*   gu_tab = (int*)((char*)d_ws + off_tabs);
    int*   dn_tab = gu_tab + 8 * SLOTS;
    unsigned short* xb     = (unsigned short*)((char*)d_ws + off_xb);
    unsigned short* interw = (unsigned short*)((char*)d_ws + off_inter);
    unsigned short* gateb  = (unsigned short*)((char*)d_ws + off_wb);
    unsigned short* upb    = gateb + NEXP * (size_t)ITR * HID;
    unsigned short* downb  = upb + NEXP * (size_t)ITR * HID;
    float* part   = (float*)((char*)d_ws + off_part);

    route_all_k<<<dim3(1), dim3(256), 0, stream>>>(idx, wts, counts, btok, bw, offs, smap, gu_tab, dn_tab);
    wconv8_k<<<dim3(NTOK * HID / 8 / 256), dim3(256), 0, stream>>>(x, xb);

    if (ws_size >= need_mid) {
        const int full = (ws_size >= need_full);
        const int wgrid = NEXP * ITR * HID / 8 / 256;   // 8192
        wconv8_k<<<dim3(wgrid), dim3(256), 0, stream>>>(gate, gateb);
        wconv8_k<<<dim3(wgrid), dim3(256), 0, stream>>>(up, upb);
        wconv8_k<<<dim3(wgrid), dim3(256), 0, stream>>>(down, downb);
        if (!full) hipMemsetAsync(d_out, 0, (size_t)out_size * sizeof(float), stream);
        moe_gu_k<<<dim3(8 * SLOTS), dim3(256), 0, stream>>>(xb, gateb, upb, counts, btok, offs, gu_tab, interw);
        moe_down_k<<<dim3(8 * SLOTS), dim3(256), 0, stream>>>(interw, downb, counts, btok, bw, offs, dn_tab,
                                                              full ? part : out, full ? 0 : 1);
        if (full)
            combine_k<<<dim3(NTOK * HID / 4 / 256), dim3(256), 0, stream>>>(part, smap, out);
    } else {
        // fp32-weight fallback (R4 path)
        hipMemsetAsync(d_out, 0, (size_t)out_size * sizeof(float), stream);
        moe_gu_f32_k<<<dim3(8 * SLOTS), dim3(256), 0, stream>>>(xb, gate, up, counts, btok, offs, gu_tab, interw);
        moe_down_f32_k<<<dim3(8 * SLOTS), dim3(256), 0, stream>>>(interw, down, counts, btok, bw, offs, dn_tab, out);
    }
}